// Round 3
// baseline (85.562 us; speedup 1.0000x reference)
//
#include <hip/hip_runtime.h>

// GIB layer: B=2, N=65536, M=8192, K=32; 16 each of cy/cone/disk/ellip gibs;
// out = mean_k(gib_vals) @ lambdas  -> (B, M, 16).
// Inputs fp32 (proven: bf16 reads NaN'd in R1), output fp32 (R2 post-mortem:
// bf16 ushort2 writes gave absmax ~= max|ref| -> buffer is fp32-read).
//
// Thread mapping: 256 thr/block = 32 queries x 8 lanes; each lane handles 4 k's.
// 64 fp32 accumulators/thread; shfl_xor reduce over 8 lanes; lambda matvec from LDS.

#define EPSF 1e-8f
#define LOG2E 1.4426950408889634f

constexpr int Mq   = 8192;
constexpr int Kc   = 32;
constexpr int QPB  = 32;   // queries per block
constexpr int KPT  = 4;    // k per thread

__global__ __launch_bounds__(256) void gib_kernel(
    const float* __restrict__ points,   // (B, 65536, 3) f32
    const float* __restrict__ qc,       // (B, 8192, 3) f32
    const int*   __restrict__ sidx,     // (B, 8192, 32) i32
    const float* __restrict__ cyp,      // (16,2)
    const float* __restrict__ conep,    // (16,2)
    const float* __restrict__ diskp,    // (16,2)
    const float* __restrict__ ellp,     // (16,3)
    const float* __restrict__ lam,      // (64,16)
    float*       __restrict__ out)      // (B, 8192, 16) f32
{
    __shared__ float pk[16][12];     // per-gib-slot derived constants
    __shared__ float lamS[64 * 16];  // lambdas * (1/32), fp32

    const int tid = threadIdx.x;

    if (tid < 16) {
        float c0 = cyp[2 * tid], c1 = cyp[2 * tid + 1];
        pk[tid][0] = c0 * c0;                         // cy center^2
        pk[tid][1] = LOG2E / (2.f * c1 * c1 + EPSF);  // cy inv-denom (log2e folded)
        float k0 = conep[2 * tid], k1 = conep[2 * tid + 1];
        pk[tid][2] = k0;
        pk[tid][3] = LOG2E / (2.f * k1 * k1 + EPSF);
        float d0 = diskp[2 * tid], d1 = diskp[2 * tid + 1];
        pk[tid][4] = LOG2E / (d0 * d0 + EPSF);
        pk[tid][5] = LOG2E / (d1 * d1 + EPSF);
        float e0 = ellp[3 * tid], e1 = ellp[3 * tid + 1], e2 = ellp[3 * tid + 2];
        pk[tid][6] = LOG2E / (e0 * e0 + EPSF);
        pk[tid][7] = LOG2E / (e1 * e1 + EPSF);
        pk[tid][8] = LOG2E / (e2 * e2 + EPSF);
        pk[tid][9] = 0.f; pk[tid][10] = 0.f; pk[tid][11] = 0.f;
    }
#pragma unroll
    for (int i = 0; i < 4; i++)
        lamS[tid * 4 + i] = lam[tid * 4 + i] * (1.0f / 32.0f);  // fold mean 1/K
    __syncthreads();

    const int q   = blockIdx.x * QPB + (tid >> 3);  // global query id in [0, B*M)
    const int sub = tid & 7;                        // lane-in-query
    const int b   = q >> 13;                        // q / 8192

    const float* qcp = qc + q * 3;
    const float qx = qcp[0], qy = qcp[1], qz = qcp[2];

    const float* ptbase = points + (size_t)b * (65536 * 3);

    // 4 contiguous indices per lane: one coalesced int4 covers the query's 32 idxs
    const int4 idx4 = ((const int4*)(sidx + q * Kc))[sub];
    const int idxs[KPT] = {idx4.x, idx4.y, idx4.z, idx4.w};

    float r2a[KPT], sa[KPT], rza[KPT], rx2a[KPT], ry2a[KPT], rz2a[KPT];
#pragma unroll
    for (int j = 0; j < KPT; j++) {
        const float* pp = ptbase + idxs[j] * 3;
        float rx = pp[0] - qx;
        float ry = pp[1] - qy;
        float rz = pp[2] - qz;
        float rx2 = rx * rx, ry2 = ry * ry, rz2 = rz * rz;
        float r2 = rx2 + ry2;
        r2a[j] = r2;
        sa[j]  = sqrtf(r2 + EPSF);
        rza[j] = rz;
        rx2a[j] = rx2; ry2a[j] = ry2; rz2a[j] = rz2;
    }

    float acc[64];
#pragma unroll
    for (int g = 0; g < 16; g++) {
        const float4 pA = *(const float4*)&pk[g][0];  // cyA, cyB, coneK, coneB
        const float4 pB = *(const float4*)&pk[g][4];  // dA, dB, eA, eB
        const float4 pC = *(const float4*)&pk[g][8];  // eC, -, -, -
        float scy = 0.f, sco = 0.f, sdk = 0.f, sel = 0.f;
#pragma unroll
        for (int j = 0; j < KPT; j++) {
            float t = r2a[j] - pA.x;
            scy += exp2f(-(t * t) * pA.y);
            float u = fmaf(-pA.z, rza[j], sa[j]);
            sco += exp2f(-(u * u) * pA.w);
            sdk += exp2f(-fmaf(r2a[j], pB.x, rz2a[j] * pB.y));
            sel += exp2f(-fmaf(rx2a[j], pB.z, fmaf(ry2a[j], pB.w, rz2a[j] * pC.x)));
        }
        acc[g]      = scy;
        acc[16 + g] = sco;
        acc[32 + g] = sdk;
        acc[48 + g] = sel;
    }

    // reduce the 64 partial sums across the 8 lanes of this query
#pragma unroll
    for (int m = 1; m < 8; m <<= 1) {
#pragma unroll
        for (int g = 0; g < 64; g++) acc[g] += __shfl_xor(acc[g], m, 64);
    }

    // lambda matvec: each lane produces 2 of the 16 observer outputs
    const int o = sub * 2;
    float s0 = 0.f, s1 = 0.f;
#pragma unroll
    for (int g = 0; g < 64; g++) {
        const float2 l = *(const float2*)&lamS[g * 16 + o];
        s0 = fmaf(acc[g], l.x, s0);
        s1 = fmaf(acc[g], l.y, s1);
    }

    float2 w;
    w.x = s0;
    w.y = s1;
    *(float2*)(out + q * 16 + o) = w;
}

extern "C" void kernel_launch(void* const* d_in, const int* in_sizes, int n_in,
                              void* d_out, int out_size, void* d_ws, size_t ws_size,
                              hipStream_t stream) {
    const float* points = (const float*)d_in[0];
    const float* qc     = (const float*)d_in[1];
    const int*   sidx   = (const int*)d_in[2];
    // d_in[3] = mc_points: unused by the reference
    const float* cyp    = (const float*)d_in[4];
    const float* conep  = (const float*)d_in[5];
    const float* diskp  = (const float*)d_in[6];
    const float* ellp   = (const float*)d_in[7];
    const float* lam    = (const float*)d_in[8];
    float*       out    = (float*)d_out;

    const int totalQ = 2 * Mq;              // B*M = 16384
    dim3 grid(totalQ / QPB), block(256);    // 512 blocks
    hipLaunchKernelGGL(gib_kernel, grid, block, 0, stream,
                       points, qc, sidx, cyp, conep, diskp, ellp, lam, out);
}